// Round 9
// baseline (86.755 us; speedup 1.0000x reference)
//
#include <hip/hip_runtime.h>
#include <hip/hip_bf16.h>
#if !__has_builtin(__builtin_amdgcn_cvt_pk_fp8_f32) || !__has_builtin(__builtin_amdgcn_cvt_pk_f32_fp8)
#include <hip/hip_fp8.h>
#endif

// ---------------- workspace layout (bytes); ws_size ~1 GB ----------------
#define CUR_OFF   0          // int cur[3]
#define SLOT_OFF  1024       // int slot_of_pos[65536]
#define POS_OFF   263168     // int posm[3][65536]
#define WSKU_OFF  1049600    // fp8 [512][384] (x64)
#define WURL_OFF  1246208    // fp8 [512][192] (x64, cols 160..192 zero)
#define WQRY_OFF  1344512    // fp8 [512][192]
#define WF8_OFF   2097152    // fp8 word table [100000][128] (x64) = 12.8 MB
#define XS_OFF    16777216   // fp8 rows, stride 384 B, 65664 rows
#define XU_OFF    50331648   // fp8 rows, stride 192 B, 65664 rows
#define XQ_OFF    68157440   // fp8 rows, stride 192 B, 65664 rows

#define NPOS      65536
#define OUT_MASK  33554432   // 65536*512
#define F8_SCALE  64.0f
#define INV4096   (1.0f / 4096.0f)

typedef __attribute__((ext_vector_type(4))) float f32x4;
typedef __attribute__((ext_vector_type(2))) float f32x2;
typedef __attribute__((ext_vector_type(2))) unsigned int u32x2;

__device__ __forceinline__ float2 ld2(const float* p) {
    return *reinterpret_cast<const float2*>(p);
}

// fp8 e4m3 (OCP) pack/unpack
__device__ __forceinline__ unsigned int pk2_f8(float a, float b) {
#if __has_builtin(__builtin_amdgcn_cvt_pk_fp8_f32)
    return __builtin_amdgcn_cvt_pk_fp8_f32(a, b, 0u, false);
#else
    __hip_fp8_e4m3 fa(a), fb(b);
    return (unsigned int)fa.__x | ((unsigned int)fb.__x << 8);
#endif
}
__device__ __forceinline__ unsigned int pk4_f8(float a, float b, float c, float d) {
#if __has_builtin(__builtin_amdgcn_cvt_pk_fp8_f32)
    unsigned int v = 0;
    v = __builtin_amdgcn_cvt_pk_fp8_f32(a, b, v, false);
    v = __builtin_amdgcn_cvt_pk_fp8_f32(c, d, v, true);
    return v;
#else
    return pk2_f8(a, b) | (pk2_f8(c, d) << 16);
#endif
}
__device__ __forceinline__ float2 upk2_f8(unsigned int u) {
#if __has_builtin(__builtin_amdgcn_cvt_pk_f32_fp8)
    f32x2 r = __builtin_amdgcn_cvt_pk_f32_fp8(u, false);
    return make_float2(r.x, r.y);
#else
    __hip_fp8_e4m3 fa, fb;
    fa.__x = (unsigned char)(u & 0xff);
    fb.__x = (unsigned char)((u >> 8) & 0xff);
    return make_float2((float)fa, (float)fb);
#endif
}
__device__ __forceinline__ void st_f8x2(unsigned char* d, float a, float b) {
    *reinterpret_cast<unsigned short*>(d) = (unsigned short)(pk2_f8(a, b) & 0xffffu);
}

#define AS1(p) ((const __attribute__((address_space(1))) void*)(p))
#define AS3(p) ((__attribute__((address_space(3))) void*)(p))

// ---- K1: word table f32->fp8(x64) + weights f32->fp8(x64) + cursor zero ----
__global__ __launch_bounds__(256) void prep_k(const float* __restrict__ sw,
                                              const float* __restrict__ uw,
                                              const float* __restrict__ qw,
                                              const float* __restrict__ word_t,
                                              char* ws) {
    const int b = blockIdx.x, t = threadIdx.x;
    if (b < 6250) {
        size_t i = ((size_t)b * 256 + t) * 8;
        f32x4 v0 = *reinterpret_cast<const f32x4*>(word_t + i);
        f32x4 v1 = *reinterpret_cast<const f32x4*>(word_t + i + 4);
        u32x2 pk;
        pk.x = pk4_f8(v0.x * F8_SCALE, v0.y * F8_SCALE, v0.z * F8_SCALE, v0.w * F8_SCALE);
        pk.y = pk4_f8(v1.x * F8_SCALE, v1.y * F8_SCALE, v1.z * F8_SCALE, v1.w * F8_SCALE);
        *reinterpret_cast<u32x2*>((unsigned char*)(ws + WF8_OFF) + i) = pk;
        return;
    }
    int tt = (b - 6250) * 256 + t;   // 393216 total
    if (tt < 3) ((int*)(ws + CUR_OFF))[tt] = 0;
    if (tt < 196608) {
        ((unsigned char*)(ws + WSKU_OFF))[tt] =
            (unsigned char)(pk2_f8(sw[tt] * F8_SCALE, 0.f) & 0xffu);
    } else if (tt < 294912) {
        int i = tt - 196608; int n = i / 192, k = i % 192;
        ((unsigned char*)(ws + WURL_OFF))[i] = (k < 160)
            ? (unsigned char)(pk2_f8(uw[n * 160 + k] * F8_SCALE, 0.f) & 0xffu) : 0;
    } else {
        int i = tt - 294912; int n = i / 192, k = i % 192;
        ((unsigned char*)(ws + WQRY_OFF))[i] = (k < 160)
            ? (unsigned char)(pk2_f8(qw[n * 160 + k] * F8_SCALE, 0.f) & 0xffu) : 0;
    }
}

// ---------------- K2: classify + slot allocation (block-aggregated) ----------
__global__ __launch_bounds__(256) void alloc_k(const int* __restrict__ et_a,
                                               float* __restrict__ out, char* ws) {
    __shared__ int s_wcnt[4][3];
    __shared__ int s_base[3];
    __shared__ int s_woff[4][3];
    const int t = threadIdx.x, lane = t & 63, wid = t >> 6;
    int p = blockIdx.x * 256 + t;
    int et = et_a[p];
    int br = (et >= 1 && et <= 3) ? 0 : (et == 4 ? 1 : (et == 5 ? 2 : -1));
    unsigned long long m0 = __ballot(br == 0);
    unsigned long long m1 = __ballot(br == 1);
    unsigned long long m2 = __ballot(br == 2);
    if (lane == 0) {
        s_wcnt[wid][0] = (int)__popcll(m0);
        s_wcnt[wid][1] = (int)__popcll(m1);
        s_wcnt[wid][2] = (int)__popcll(m2);
    }
    __syncthreads();
    if (t < 3) {
        int c0 = s_wcnt[0][t], c1 = s_wcnt[1][t], c2 = s_wcnt[2][t], c3 = s_wcnt[3][t];
        int tot = c0 + c1 + c2 + c3;
        s_base[t] = tot ? atomicAdd(&((int*)(ws + CUR_OFF))[t], tot) : 0;
        s_woff[0][t] = 0; s_woff[1][t] = c0; s_woff[2][t] = c0 + c1; s_woff[3][t] = c0 + c1 + c2;
    }
    __syncthreads();
    unsigned long long lt = (1ull << lane) - 1ull;
    int slot = -1;
    if (br == 0)      slot = s_base[0] + s_woff[wid][0] + (int)__popcll(m0 & lt);
    else if (br == 1) slot = s_base[1] + s_woff[wid][1] + (int)__popcll(m1 & lt);
    else if (br == 2) slot = s_base[2] + s_woff[wid][2] + (int)__popcll(m2 & lt);
    ((int*)(ws + SLOT_OFF))[p] = slot;
    if (slot >= 0) ((int*)(ws + POS_OFF))[br * NPOS + slot] = p;
    __builtin_nontemporal_store((et == 0) ? 1.0f : 0.0f, &out[OUT_MASK + p]);
}

// ---------------- K3: build fp8 input rows (x64 domain), 1 pos/wave ---------
__device__ __forceinline__ float2 wsum_f8(const unsigned char* __restrict__ wt8,
                                          const int* __restrict__ wids, int lane) {
    float sx = 0.f, sy = 0.f;
    #pragma unroll
    for (int k = 0; k < 12; ++k) {
        unsigned int u = *reinterpret_cast<const unsigned short*>(
            wt8 + (size_t)wids[k] * 128 + 2 * lane);
        float2 v = upk2_f8(u);
        sx += v.x; sy += v.y;
    }
    const float inv = 1.0f / 12.0f;      // stays in x64 domain
    return make_float2(sx * inv, sy * inv);
}

__global__ __launch_bounds__(256) void build_k(
    const float* __restrict__ ev_t,
    const float* __restrict__ sku_t,  const float* __restrict__ cat_t,
    const float* __restrict__ price_t,const float* __restrict__ url_t,
    const int* __restrict__ et_a,     const int* __restrict__ sku_id,
    const int* __restrict__ url_id,   const int* __restrict__ cat_id,
    const int* __restrict__ price_id, const int* __restrict__ word_id,
    float* __restrict__ out, char* ws)
{
    const int t = threadIdx.x, lane = t & 63, wid = t >> 6;
    const int p = blockIdx.x * 4 + wid;
    const int et = et_a[p];
    if (et == 0) {  // pad: zero output row
        f32x4 z = {0.f, 0.f, 0.f, 0.f};
        float* orow = out + (size_t)p * 512;
        __builtin_nontemporal_store(z, reinterpret_cast<f32x4*>(&orow[lane * 8]));
        __builtin_nontemporal_store(z, reinterpret_cast<f32x4*>(&orow[lane * 8 + 4]));
        return;
    }
    const int slot = ((const int*)(ws + SLOT_OFF))[p];
    const unsigned char* wf8 = (const unsigned char*)(ws + WF8_OFF);
    const float* evr = ev_t + et * 32;
    if (et <= 3) {  // sku row: [ev 0..32)[sku 32..160)[cat 160..224)[price 224..256)[word 256..384)
        unsigned char* X = (unsigned char*)(ws + XS_OFF) + (size_t)slot * 384;
        if (lane < 16) { float2 e = ld2(evr + 2 * lane);
                         st_f8x2(X + 2 * lane, e.x * F8_SCALE, e.y * F8_SCALE); }
        const float* sr = sku_t + (size_t)sku_id[p] * 128;
        { float2 s = ld2(sr + 2 * lane);
          st_f8x2(X + 32 + 2 * lane, s.x * F8_SCALE, s.y * F8_SCALE); }
        if (lane < 32) { const float* cr = cat_t + (size_t)cat_id[p] * 64;
                         float2 c = ld2(cr + 2 * lane);
                         st_f8x2(X + 160 + 2 * lane, c.x * F8_SCALE, c.y * F8_SCALE); }
        if (lane < 16) { const float* pr = price_t + (size_t)price_id[p] * 32;
                         float2 v = ld2(pr + 2 * lane);
                         st_f8x2(X + 224 + 2 * lane, v.x * F8_SCALE, v.y * F8_SCALE); }
        float2 w = wsum_f8(wf8, word_id + (size_t)p * 12, lane);
        st_f8x2(X + 256 + 2 * lane, w.x, w.y);
    } else if (et == 4) {  // url row: [url 0..128)[ev 128..160)[zero 160..192)
        unsigned char* X = (unsigned char*)(ws + XU_OFF) + (size_t)slot * 192;
        const float* ur = url_t + (size_t)url_id[p] * 128;
        { float2 u = ld2(ur + 2 * lane);
          st_f8x2(X + 2 * lane, u.x * F8_SCALE, u.y * F8_SCALE); }
        if (lane < 16) { float2 e = ld2(evr + 2 * lane);
                         st_f8x2(X + 128 + 2 * lane, e.x * F8_SCALE, e.y * F8_SCALE); }
        if (lane >= 48) *reinterpret_cast<unsigned short*>(X + 160 + 2 * (lane - 48)) = 0;
    } else {               // query row: [ev 0..32)[word 32..160)[zero 160..192)
        unsigned char* X = (unsigned char*)(ws + XQ_OFF) + (size_t)slot * 192;
        if (lane < 16) { float2 e = ld2(evr + 2 * lane);
                         st_f8x2(X + 2 * lane, e.x * F8_SCALE, e.y * F8_SCALE); }
        float2 w = wsum_f8(wf8, word_id + (size_t)p * 12, lane);
        st_f8x2(X + 32 + 2 * lane, w.x, w.y);
        if (lane >= 48) *reinterpret_cast<unsigned short*>(X + 160 + 2 * (lane - 48)) = 0;
    }
}

// ---------------- K4: merged fp8 branch GEMMs  out[pos]=relu(X*W^T/4096+b) --
// 128x128 tile, 4 waves (2x2) x 64x64, mfma_f32_16x16x32_fp8_fp8.
// K-plan: sku 3x128B tiles; url/qry 128B + 64B tiles (K=192).
// T2 swizzle per tile width: linear LDS dest, pre-swizzled source, XOR'd reads.
__global__ __launch_bounds__(256, 2) void gemm_all_k(
    const char* __restrict__ ws_c, const float* __restrict__ sku_b,
    const float* __restrict__ url_b, const float* __restrict__ qry_b,
    float* __restrict__ out)
{
    const int z = blockIdx.z;
    const int count = ((const int*)(ws_c + CUR_OFF))[z];
    const int nmt = (count + 127) >> 7;
    const int nwg = nmt * 4;
    const int orig = blockIdx.x;
    if (orig >= nwg) return;
    const int q8 = nwg >> 3, r8 = nwg & 7;
    const int xcd = orig & 7, idx = orig >> 3;
    const int wg = (xcd < r8 ? xcd * (q8 + 1) : r8 * (q8 + 1) + (xcd - r8) * q8) + idx;
    const int mt = wg >> 2;
    const int row0 = mt * 128;
    const int nc0  = (wg & 3) * 128;

    const char* arena; const char* Wb; const float* bias; const int* posm;
    int astride, nkt;
    if (z == 0) { arena = ws_c + XS_OFF; Wb = ws_c + WSKU_OFF; bias = sku_b;
                  posm = (const int*)(ws_c + POS_OFF);          astride = 384; nkt = 3; }
    else if (z == 1) { arena = ws_c + XU_OFF; Wb = ws_c + WURL_OFF; bias = url_b;
                  posm = (const int*)(ws_c + POS_OFF) + NPOS;   astride = 192; nkt = 2; }
    else       { arena = ws_c + XQ_OFF; Wb = ws_c + WQRY_OFF; bias = qry_b;
                  posm = (const int*)(ws_c + POS_OFF) + 2*NPOS; astride = 192; nkt = 2; }

    __shared__ char lds[2][2][16384];   // [buf][A/B][<=128 rows x 128 B]

    const int t = threadIdx.x;
    const int lane = t & 63;
    const int wid  = t >> 6;
    const int wr = wid >> 1, wc = wid & 1;
    const int r = lane & 15, q = lane >> 4;

    // full==true: 128-B tile at koff; full==false: 64-B tile at koff
    auto stage = [&](int buf, int koff, bool full) {
        if (full) {
            #pragma unroll
            for (int i = 0; i < 4; ++i) {
                int row = i * 32 + (t >> 3);
                int sb  = (t & 7) ^ (row & 7);
                const char* ga = arena + (size_t)(row0 + row) * astride + koff + sb * 16;
                __builtin_amdgcn_global_load_lds(AS1(ga), AS3(&lds[buf][0][i * 4096 + t * 16]), 16, 0, 0);
                const char* gb = Wb + (size_t)(nc0 + row) * astride + koff + sb * 16;
                __builtin_amdgcn_global_load_lds(AS1(gb), AS3(&lds[buf][1][i * 4096 + t * 16]), 16, 0, 0);
            }
        } else {
            #pragma unroll
            for (int i = 0; i < 2; ++i) {
                int row = i * 64 + (t >> 2);
                int sb  = (t & 3) ^ (row & 3);
                const char* ga = arena + (size_t)(row0 + row) * astride + koff + sb * 16;
                __builtin_amdgcn_global_load_lds(AS1(ga), AS3(&lds[buf][0][i * 4096 + t * 16]), 16, 0, 0);
                const char* gb = Wb + (size_t)(nc0 + row) * astride + koff + sb * 16;
                __builtin_amdgcn_global_load_lds(AS1(gb), AS3(&lds[buf][1][i * 4096 + t * 16]), 16, 0, 0);
            }
        }
    };

    f32x4 acc[4][4];
    #pragma unroll
    for (int m = 0; m < 4; ++m)
        #pragma unroll
        for (int n = 0; n < 4; ++n)
            acc[m][n] = (f32x4){0.f, 0.f, 0.f, 0.f};

    stage(0, 0, true);
    __syncthreads();
    int cur = 0;
    for (int kt = 0; kt < nkt; ++kt) {
        const bool full = (z == 0) || (kt == 0);         // this tile's width
        if (kt + 1 < nkt) stage(cur ^ 1, (kt + 1) * 128, (z == 0));
        if (full) {
            #pragma unroll
            for (int kk = 0; kk < 4; ++kk) {
                const int u  = kk * 2 + (q >> 1);
                const int wo = (q & 1) * 8;
                long af[4], bfr[4];
                #pragma unroll
                for (int m = 0; m < 4; ++m) {
                    int arow = wr * 64 + m * 16 + r;
                    af[m] = *reinterpret_cast<const long*>(
                        &lds[cur][0][arow * 128 + ((u ^ (arow & 7)) << 4) + wo]);
                }
                #pragma unroll
                for (int n = 0; n < 4; ++n) {
                    int brow = wc * 64 + n * 16 + r;
                    bfr[n] = *reinterpret_cast<const long*>(
                        &lds[cur][1][brow * 128 + ((u ^ (brow & 7)) << 4) + wo]);
                }
                #pragma unroll
                for (int m = 0; m < 4; ++m)
                    #pragma unroll
                    for (int n = 0; n < 4; ++n)
                        acc[m][n] = __builtin_amdgcn_mfma_f32_16x16x32_fp8_fp8(af[m], bfr[n], acc[m][n], 0, 0, 0);
            }
        } else {
            #pragma unroll
            for (int kk = 0; kk < 2; ++kk) {
                const int u  = kk * 2 + (q >> 1);        // unit 0..3 of 64-B row
                const int wo = (q & 1) * 8;
                long af[4], bfr[4];
                #pragma unroll
                for (int m = 0; m < 4; ++m) {
                    int arow = wr * 64 + m * 16 + r;
                    af[m] = *reinterpret_cast<const long*>(
                        &lds[cur][0][arow * 64 + ((u ^ (arow & 3)) << 4) + wo]);
                }
                #pragma unroll
                for (int n = 0; n < 4; ++n) {
                    int brow = wc * 64 + n * 16 + r;
                    bfr[n] = *reinterpret_cast<const long*>(
                        &lds[cur][1][brow * 64 + ((u ^ (brow & 3)) << 4) + wo]);
                }
                #pragma unroll
                for (int m = 0; m < 4; ++m)
                    #pragma unroll
                    for (int n = 0; n < 4; ++n)
                        acc[m][n] = __builtin_amdgcn_mfma_f32_16x16x32_fp8_fp8(af[m], bfr[n], acc[m][n], 0, 0, 0);
            }
        }
        __syncthreads();
        cur ^= 1;
    }

    float bv[4];
    #pragma unroll
    for (int n = 0; n < 4; ++n) bv[n] = bias[nc0 + wc * 64 + n * 16 + r];
    #pragma unroll
    for (int m = 0; m < 4; ++m) {
        #pragma unroll
        for (int j = 0; j < 4; ++j) {
            int rl = wr * 64 + m * 16 + q * 4 + j;
            int gr = row0 + rl;
            if (gr < count) {
                int pos = posm[gr];
                float* orow = out + (size_t)pos * 512 + nc0 + wc * 64;
                #pragma unroll
                for (int n = 0; n < 4; ++n)
                    __builtin_nontemporal_store(
                        fmaxf(acc[m][n][j] * INV4096 + bv[n], 0.f), &orow[n * 16 + r]);
            }
        }
    }
}

// ---------------- host ----------------
extern "C" void kernel_launch(void* const* d_in, const int* in_sizes, int n_in,
                              void* d_out, int out_size, void* d_ws, size_t ws_size,
                              hipStream_t stream) {
    const float* ev_t    = (const float*)d_in[0];
    const float* word_t  = (const float*)d_in[1];
    const float* sku_t   = (const float*)d_in[2];
    const float* cat_t   = (const float*)d_in[3];
    const float* price_t = (const float*)d_in[4];
    const float* url_t   = (const float*)d_in[5];
    const float* sku_w   = (const float*)d_in[6];
    const float* sku_b   = (const float*)d_in[7];
    const float* url_w   = (const float*)d_in[8];
    const float* url_b   = (const float*)d_in[9];
    const float* query_w = (const float*)d_in[10];
    const float* query_b = (const float*)d_in[11];
    const int* event_type = (const int*)d_in[12];
    const int* sku_id     = (const int*)d_in[13];
    const int* url_id     = (const int*)d_in[14];
    const int* cat_id     = (const int*)d_in[15];
    const int* price_id   = (const int*)d_in[16];
    const int* word_id    = (const int*)d_in[17];

    char*  ws  = (char*)d_ws;
    float* out = (float*)d_out;

    prep_k<<<7786, 256, 0, stream>>>(sku_w, url_w, query_w, word_t, ws);
    alloc_k<<<256, 256, 0, stream>>>(event_type, out, ws);
    build_k<<<16384, 256, 0, stream>>>(ev_t, sku_t, cat_t, price_t, url_t,
                                       event_type, sku_id, url_id, cat_id, price_id,
                                       word_id, out, ws);
    dim3 gg(2048, 1, 3);
    gemm_all_k<<<gg, 256, 0, stream>>>(ws, sku_b, url_b, query_b, out);
}

// Round 10
// 86.279 us; speedup vs baseline: 1.0055x; 1.0055x over previous
//
#include <hip/hip_runtime.h>
#include <hip/hip_bf16.h>
#if !__has_builtin(__builtin_amdgcn_cvt_pk_fp8_f32) || !__has_builtin(__builtin_amdgcn_cvt_pk_f32_fp8)
#include <hip/hip_fp8.h>
#endif

// ---------------- workspace layout (bytes); ws_size ~1 GB ----------------
#define CUR_OFF   0          // int cur[3]
#define SLOT_OFF  1024       // int slot_of_pos[65536]
#define POS_OFF   263168     // int posm[3][65536]
#define WSKU_OFF  1049600    // fp8 [512][384] (x64)
#define WURL_OFF  1246208    // fp8 [512][192] (x64, cols 160..192 zero)
#define WQRY_OFF  1344512    // fp8 [512][192]
#define WF8_OFF   2097152    // fp8 word table [100000][128] (x64) = 12.8 MB
#define XS_OFF    16777216   // fp8 rows, stride 384 B, 65664 rows
#define XU_OFF    50331648   // fp8 rows, stride 192 B, 65664 rows
#define XQ_OFF    68157440   // fp8 rows, stride 192 B, 65664 rows

#define NPOS      65536
#define OUT_MASK  33554432   // 65536*512
#define F8_SCALE  64.0f
#define INV4096   (1.0f / 4096.0f)

typedef __attribute__((ext_vector_type(4))) float f32x4;
typedef __attribute__((ext_vector_type(2))) float f32x2;
typedef __attribute__((ext_vector_type(2))) unsigned int u32x2;

__device__ __forceinline__ float2 ld2(const float* p) {
    return *reinterpret_cast<const float2*>(p);
}

// fp8 e4m3 (OCP) pack/unpack
__device__ __forceinline__ unsigned int pk2_f8(float a, float b) {
#if __has_builtin(__builtin_amdgcn_cvt_pk_fp8_f32)
    return __builtin_amdgcn_cvt_pk_fp8_f32(a, b, 0u, false);
#else
    __hip_fp8_e4m3 fa(a), fb(b);
    return (unsigned int)fa.__x | ((unsigned int)fb.__x << 8);
#endif
}
__device__ __forceinline__ unsigned int pk4_f8(float a, float b, float c, float d) {
#if __has_builtin(__builtin_amdgcn_cvt_pk_fp8_f32)
    unsigned int v = 0;
    v = __builtin_amdgcn_cvt_pk_fp8_f32(a, b, v, false);
    v = __builtin_amdgcn_cvt_pk_fp8_f32(c, d, v, true);
    return v;
#else
    return pk2_f8(a, b) | (pk2_f8(c, d) << 16);
#endif
}
__device__ __forceinline__ float2 upk2_f8(unsigned int u) {
#if __has_builtin(__builtin_amdgcn_cvt_pk_f32_fp8)
    f32x2 r = __builtin_amdgcn_cvt_pk_f32_fp8(u, false);
    return make_float2(r.x, r.y);
#else
    __hip_fp8_e4m3 fa, fb;
    fa.__x = (unsigned char)(u & 0xff);
    fb.__x = (unsigned char)((u >> 8) & 0xff);
    return make_float2((float)fa, (float)fb);
#endif
}
__device__ __forceinline__ void st_f8x2(unsigned char* d, float a, float b) {
    *reinterpret_cast<unsigned short*>(d) = (unsigned short)(pk2_f8(a, b) & 0xffffu);
}

#define AS1(p) ((const __attribute__((address_space(1))) void*)(p))
#define AS3(p) ((__attribute__((address_space(3))) void*)(p))

// counted-wait pipeline primitives (T4; rule #18 fencing)
#define WAITV0() asm volatile("s_waitcnt vmcnt(0)" ::: "memory")
#define WAITV4() asm volatile("s_waitcnt vmcnt(4)" ::: "memory")
#define WAITV8() asm volatile("s_waitcnt vmcnt(8)" ::: "memory")
#define WAITL()  asm volatile("s_waitcnt lgkmcnt(0)" ::: "memory")
#define BARR()   __builtin_amdgcn_s_barrier()
#define FENCE()  __builtin_amdgcn_sched_barrier(0)

// ---- K1: word table f32->fp8(x64) + weights f32->fp8(x64) + cursor zero ----
__global__ __launch_bounds__(256) void prep_k(const float* __restrict__ sw,
                                              const float* __restrict__ uw,
                                              const float* __restrict__ qw,
                                              const float* __restrict__ word_t,
                                              char* ws) {
    const int b = blockIdx.x, t = threadIdx.x;
    if (b < 6250) {
        size_t i = ((size_t)b * 256 + t) * 8;
        f32x4 v0 = *reinterpret_cast<const f32x4*>(word_t + i);
        f32x4 v1 = *reinterpret_cast<const f32x4*>(word_t + i + 4);
        u32x2 pk;
        pk.x = pk4_f8(v0.x * F8_SCALE, v0.y * F8_SCALE, v0.z * F8_SCALE, v0.w * F8_SCALE);
        pk.y = pk4_f8(v1.x * F8_SCALE, v1.y * F8_SCALE, v1.z * F8_SCALE, v1.w * F8_SCALE);
        *reinterpret_cast<u32x2*>((unsigned char*)(ws + WF8_OFF) + i) = pk;
        return;
    }
    int tt = (b - 6250) * 256 + t;   // 393216 total
    if (tt < 3) ((int*)(ws + CUR_OFF))[tt] = 0;
    if (tt < 196608) {
        ((unsigned char*)(ws + WSKU_OFF))[tt] =
            (unsigned char)(pk2_f8(sw[tt] * F8_SCALE, 0.f) & 0xffu);
    } else if (tt < 294912) {
        int i = tt - 196608; int n = i / 192, k = i % 192;
        ((unsigned char*)(ws + WURL_OFF))[i] = (k < 160)
            ? (unsigned char)(pk2_f8(uw[n * 160 + k] * F8_SCALE, 0.f) & 0xffu) : 0;
    } else {
        int i = tt - 294912; int n = i / 192, k = i % 192;
        ((unsigned char*)(ws + WQRY_OFF))[i] = (k < 160)
            ? (unsigned char)(pk2_f8(qw[n * 160 + k] * F8_SCALE, 0.f) & 0xffu) : 0;
    }
}

// ---------------- K2: classify + slot allocation (block-aggregated) ----------
__global__ __launch_bounds__(256) void alloc_k(const int* __restrict__ et_a,
                                               float* __restrict__ out, char* ws) {
    __shared__ int s_wcnt[4][3];
    __shared__ int s_base[3];
    __shared__ int s_woff[4][3];
    const int t = threadIdx.x, lane = t & 63, wid = t >> 6;
    int p = blockIdx.x * 256 + t;
    int et = et_a[p];
    int br = (et >= 1 && et <= 3) ? 0 : (et == 4 ? 1 : (et == 5 ? 2 : -1));
    unsigned long long m0 = __ballot(br == 0);
    unsigned long long m1 = __ballot(br == 1);
    unsigned long long m2 = __ballot(br == 2);
    if (lane == 0) {
        s_wcnt[wid][0] = (int)__popcll(m0);
        s_wcnt[wid][1] = (int)__popcll(m1);
        s_wcnt[wid][2] = (int)__popcll(m2);
    }
    __syncthreads();
    if (t < 3) {
        int c0 = s_wcnt[0][t], c1 = s_wcnt[1][t], c2 = s_wcnt[2][t], c3 = s_wcnt[3][t];
        int tot = c0 + c1 + c2 + c3;
        s_base[t] = tot ? atomicAdd(&((int*)(ws + CUR_OFF))[t], tot) : 0;
        s_woff[0][t] = 0; s_woff[1][t] = c0; s_woff[2][t] = c0 + c1; s_woff[3][t] = c0 + c1 + c2;
    }
    __syncthreads();
    unsigned long long lt = (1ull << lane) - 1ull;
    int slot = -1;
    if (br == 0)      slot = s_base[0] + s_woff[wid][0] + (int)__popcll(m0 & lt);
    else if (br == 1) slot = s_base[1] + s_woff[wid][1] + (int)__popcll(m1 & lt);
    else if (br == 2) slot = s_base[2] + s_woff[wid][2] + (int)__popcll(m2 & lt);
    ((int*)(ws + SLOT_OFF))[p] = slot;
    if (slot >= 0) ((int*)(ws + POS_OFF))[br * NPOS + slot] = p;
    __builtin_nontemporal_store((et == 0) ? 1.0f : 0.0f, &out[OUT_MASK + p]);
}

// ---------------- K3: build fp8 input rows (x64 domain), 1 pos/wave ---------
__device__ __forceinline__ float2 wsum_f8(const unsigned char* __restrict__ wt8,
                                          const int* __restrict__ wids, int lane) {
    float sx = 0.f, sy = 0.f;
    #pragma unroll
    for (int k = 0; k < 12; ++k) {
        unsigned int u = *reinterpret_cast<const unsigned short*>(
            wt8 + (size_t)wids[k] * 128 + 2 * lane);
        float2 v = upk2_f8(u);
        sx += v.x; sy += v.y;
    }
    const float inv = 1.0f / 12.0f;      // stays in x64 domain
    return make_float2(sx * inv, sy * inv);
}

__global__ __launch_bounds__(256) void build_k(
    const float* __restrict__ ev_t,
    const float* __restrict__ sku_t,  const float* __restrict__ cat_t,
    const float* __restrict__ price_t,const float* __restrict__ url_t,
    const int* __restrict__ et_a,     const int* __restrict__ sku_id,
    const int* __restrict__ url_id,   const int* __restrict__ cat_id,
    const int* __restrict__ price_id, const int* __restrict__ word_id,
    float* __restrict__ out, char* ws)
{
    const int t = threadIdx.x, lane = t & 63, wid = t >> 6;
    const int p = blockIdx.x * 4 + wid;
    const int et = et_a[p];
    if (et == 0) {  // pad: zero output row
        f32x4 z = {0.f, 0.f, 0.f, 0.f};
        float* orow = out + (size_t)p * 512;
        __builtin_nontemporal_store(z, reinterpret_cast<f32x4*>(&orow[lane * 8]));
        __builtin_nontemporal_store(z, reinterpret_cast<f32x4*>(&orow[lane * 8 + 4]));
        return;
    }
    const int slot = ((const int*)(ws + SLOT_OFF))[p];
    const unsigned char* wf8 = (const unsigned char*)(ws + WF8_OFF);
    const float* evr = ev_t + et * 32;
    if (et <= 3) {  // sku row: [ev 0..32)[sku 32..160)[cat 160..224)[price 224..256)[word 256..384)
        unsigned char* X = (unsigned char*)(ws + XS_OFF) + (size_t)slot * 384;
        if (lane < 16) { float2 e = ld2(evr + 2 * lane);
                         st_f8x2(X + 2 * lane, e.x * F8_SCALE, e.y * F8_SCALE); }
        const float* sr = sku_t + (size_t)sku_id[p] * 128;
        { float2 s = ld2(sr + 2 * lane);
          st_f8x2(X + 32 + 2 * lane, s.x * F8_SCALE, s.y * F8_SCALE); }
        if (lane < 32) { const float* cr = cat_t + (size_t)cat_id[p] * 64;
                         float2 c = ld2(cr + 2 * lane);
                         st_f8x2(X + 160 + 2 * lane, c.x * F8_SCALE, c.y * F8_SCALE); }
        if (lane < 16) { const float* pr = price_t + (size_t)price_id[p] * 32;
                         float2 v = ld2(pr + 2 * lane);
                         st_f8x2(X + 224 + 2 * lane, v.x * F8_SCALE, v.y * F8_SCALE); }
        float2 w = wsum_f8(wf8, word_id + (size_t)p * 12, lane);
        st_f8x2(X + 256 + 2 * lane, w.x, w.y);
    } else if (et == 4) {  // url row: [url 0..128)[ev 128..160)[zero 160..192)
        unsigned char* X = (unsigned char*)(ws + XU_OFF) + (size_t)slot * 192;
        const float* ur = url_t + (size_t)url_id[p] * 128;
        { float2 u = ld2(ur + 2 * lane);
          st_f8x2(X + 2 * lane, u.x * F8_SCALE, u.y * F8_SCALE); }
        if (lane < 16) { float2 e = ld2(evr + 2 * lane);
                         st_f8x2(X + 128 + 2 * lane, e.x * F8_SCALE, e.y * F8_SCALE); }
        if (lane >= 48) *reinterpret_cast<unsigned short*>(X + 160 + 2 * (lane - 48)) = 0;
    } else {               // query row: [ev 0..32)[word 32..160)[zero 160..192)
        unsigned char* X = (unsigned char*)(ws + XQ_OFF) + (size_t)slot * 192;
        if (lane < 16) { float2 e = ld2(evr + 2 * lane);
                         st_f8x2(X + 2 * lane, e.x * F8_SCALE, e.y * F8_SCALE); }
        float2 w = wsum_f8(wf8, word_id + (size_t)p * 12, lane);
        st_f8x2(X + 32 + 2 * lane, w.x, w.y);
        if (lane >= 48) *reinterpret_cast<unsigned short*>(X + 160 + 2 * (lane - 48)) = 0;
    }
}

// ---------------- K4: merged fp8 branch GEMMs  out[pos]=relu(X*W^T/4096+b) --
// 128x128 tile, 4 waves (2x2) x 64x64, mfma_f32_16x16x32_fp8_fp8.
// T4 counted-vmcnt pipeline: all stages issued early; per K-step
//   s_waitcnt vmcnt(N_outstanding_next) + raw s_barrier (loads stay in flight);
//   buffer-reuse protected by lgkmcnt(0)+barrier (no vmcnt drain).
__global__ __launch_bounds__(256, 2) void gemm_all_k(
    const char* __restrict__ ws_c, const float* __restrict__ sku_b,
    const float* __restrict__ url_b, const float* __restrict__ qry_b,
    float* __restrict__ out)
{
    const int z = blockIdx.z;
    const int count = ((const int*)(ws_c + CUR_OFF))[z];
    const int nmt = (count + 127) >> 7;
    const int nwg = nmt * 4;
    const int orig = blockIdx.x;
    if (orig >= nwg) return;
    const int q8 = nwg >> 3, r8 = nwg & 7;
    const int xcd = orig & 7, idx = orig >> 3;
    const int wg = (xcd < r8 ? xcd * (q8 + 1) : r8 * (q8 + 1) + (xcd - r8) * q8) + idx;
    const int mt = wg >> 2;
    const int row0 = mt * 128;
    const int nc0  = (wg & 3) * 128;

    const char* arena; const char* Wb; const float* bias; const int* posm;
    int astride;
    if (z == 0) { arena = ws_c + XS_OFF; Wb = ws_c + WSKU_OFF; bias = sku_b;
                  posm = (const int*)(ws_c + POS_OFF);          astride = 384; }
    else if (z == 1) { arena = ws_c + XU_OFF; Wb = ws_c + WURL_OFF; bias = url_b;
                  posm = (const int*)(ws_c + POS_OFF) + NPOS;   astride = 192; }
    else       { arena = ws_c + XQ_OFF; Wb = ws_c + WQRY_OFF; bias = qry_b;
                  posm = (const int*)(ws_c + POS_OFF) + 2*NPOS; astride = 192; }

    __shared__ char lds[2][2][16384];   // [buf][A/B][<=128 rows x 128 B]

    const int t = threadIdx.x;
    const int lane = t & 63;
    const int wid  = t >> 6;
    const int wr = wid >> 1, wc = wid & 1;
    const int r = lane & 15, q = lane >> 4;

    // 8 gload_lds per thread
    auto stage_full = [&](int buf, int koff) {
        #pragma unroll
        for (int i = 0; i < 4; ++i) {
            int row = i * 32 + (t >> 3);
            int sb  = (t & 7) ^ (row & 7);
            const char* ga = arena + (size_t)(row0 + row) * astride + koff + sb * 16;
            __builtin_amdgcn_global_load_lds(AS1(ga), AS3(&lds[buf][0][i * 4096 + t * 16]), 16, 0, 0);
            const char* gb = Wb + (size_t)(nc0 + row) * astride + koff + sb * 16;
            __builtin_amdgcn_global_load_lds(AS1(gb), AS3(&lds[buf][1][i * 4096 + t * 16]), 16, 0, 0);
        }
    };
    // 4 gload_lds per thread (64-B-wide tile)
    auto stage_half = [&](int buf, int koff) {
        #pragma unroll
        for (int i = 0; i < 2; ++i) {
            int row = i * 64 + (t >> 2);
            int sb  = (t & 3) ^ (row & 3);
            const char* ga = arena + (size_t)(row0 + row) * astride + koff + sb * 16;
            __builtin_amdgcn_global_load_lds(AS1(ga), AS3(&lds[buf][0][i * 4096 + t * 16]), 16, 0, 0);
            const char* gb = Wb + (size_t)(nc0 + row) * astride + koff + sb * 16;
            __builtin_amdgcn_global_load_lds(AS1(gb), AS3(&lds[buf][1][i * 4096 + t * 16]), 16, 0, 0);
        }
    };

    f32x4 acc[4][4];
    #pragma unroll
    for (int m = 0; m < 4; ++m)
        #pragma unroll
        for (int n = 0; n < 4; ++n)
            acc[m][n] = (f32x4){0.f, 0.f, 0.f, 0.f};

    auto comp_full = [&](int buf) {
        #pragma unroll
        for (int kk = 0; kk < 4; ++kk) {
            const int u  = kk * 2 + (q >> 1);
            const int wo = (q & 1) * 8;
            long af[4], bfr[4];
            #pragma unroll
            for (int m = 0; m < 4; ++m) {
                int arow = wr * 64 + m * 16 + r;
                af[m] = *reinterpret_cast<const long*>(
                    &lds[buf][0][arow * 128 + ((u ^ (arow & 7)) << 4) + wo]);
            }
            #pragma unroll
            for (int n = 0; n < 4; ++n) {
                int brow = wc * 64 + n * 16 + r;
                bfr[n] = *reinterpret_cast<const long*>(
                    &lds[buf][1][brow * 128 + ((u ^ (brow & 7)) << 4) + wo]);
            }
            #pragma unroll
            for (int m = 0; m < 4; ++m)
                #pragma unroll
                for (int n = 0; n < 4; ++n)
                    acc[m][n] = __builtin_amdgcn_mfma_f32_16x16x32_fp8_fp8(af[m], bfr[n], acc[m][n], 0, 0, 0);
        }
    };
    auto comp_half = [&](int buf) {
        #pragma unroll
        for (int kk = 0; kk < 2; ++kk) {
            const int u  = kk * 2 + (q >> 1);
            const int wo = (q & 1) * 8;
            long af[4], bfr[4];
            #pragma unroll
            for (int m = 0; m < 4; ++m) {
                int arow = wr * 64 + m * 16 + r;
                af[m] = *reinterpret_cast<const long*>(
                    &lds[buf][0][arow * 64 + ((u ^ (arow & 3)) << 4) + wo]);
            }
            #pragma unroll
            for (int n = 0; n < 4; ++n) {
                int brow = wc * 64 + n * 16 + r;
                bfr[n] = *reinterpret_cast<const long*>(
                    &lds[buf][1][brow * 64 + ((u ^ (brow & 3)) << 4) + wo]);
            }
            #pragma unroll
            for (int m = 0; m < 4; ++m)
                #pragma unroll
                for (int n = 0; n < 4; ++n)
                    acc[m][n] = __builtin_amdgcn_mfma_f32_16x16x32_fp8_fp8(af[m], bfr[n], acc[m][n], 0, 0, 0);
        }
    };

    if (z == 0) {                       // K=384: three full tiles
        stage_full(0, 0);
        stage_full(1, 128);             // 16 loads in flight
        WAITV8(); BARR(); FENCE();      // tile0 landed; tile1 stays in flight
        comp_full(0);
        WAITL(); BARR(); FENCE();       // all waves done reading buf0
        stage_full(0, 256);             // overwrite buf0 with tile2
        WAITV8(); BARR(); FENCE();      // tile1 landed; tile2 in flight
        comp_full(1);
        WAITV0(); BARR(); FENCE();      // tile2 landed
        comp_full(0);
    } else {                            // K=192: full + half tile
        stage_full(0, 0);
        stage_half(1, 128);             // 12 loads in flight
        WAITV4(); BARR(); FENCE();      // tile0 landed; half-tile in flight
        comp_full(0);
        WAITV0(); BARR(); FENCE();      // half-tile landed
        comp_half(1);
    }

    float bv[4];
    #pragma unroll
    for (int n = 0; n < 4; ++n) bv[n] = bias[nc0 + wc * 64 + n * 16 + r];
    #pragma unroll
    for (int m = 0; m < 4; ++m) {
        #pragma unroll
        for (int j = 0; j < 4; ++j) {
            int rl = wr * 64 + m * 16 + q * 4 + j;
            int gr = row0 + rl;
            if (gr < count) {
                int pos = posm[gr];
                float* orow = out + (size_t)pos * 512 + nc0 + wc * 64;
                #pragma unroll
                for (int n = 0; n < 4; ++n)
                    __builtin_nontemporal_store(
                        fmaxf(acc[m][n][j] * INV4096 + bv[n], 0.f), &orow[n * 16 + r]);
            }
        }
    }
}

// ---------------- host ----------------
extern "C" void kernel_launch(void* const* d_in, const int* in_sizes, int n_in,
                              void* d_out, int out_size, void* d_ws, size_t ws_size,
                              hipStream_t stream) {
    const float* ev_t    = (const float*)d_in[0];
    const float* word_t  = (const float*)d_in[1];
    const float* sku_t   = (const float*)d_in[2];
    const float* cat_t   = (const float*)d_in[3];
    const float* price_t = (const float*)d_in[4];
    const float* url_t   = (const float*)d_in[5];
    const float* sku_w   = (const float*)d_in[6];
    const float* sku_b   = (const float*)d_in[7];
    const float* url_w   = (const float*)d_in[8];
    const float* url_b   = (const float*)d_in[9];
    const float* query_w = (const float*)d_in[10];
    const float* query_b = (const float*)d_in[11];
    const int* event_type = (const int*)d_in[12];
    const int* sku_id     = (const int*)d_in[13];
    const int* url_id     = (const int*)d_in[14];
    const int* cat_id     = (const int*)d_in[15];
    const int* price_id   = (const int*)d_in[16];
    const int* word_id    = (const int*)d_in[17];

    char*  ws  = (char*)d_ws;
    float* out = (float*)d_out;

    prep_k<<<7786, 256, 0, stream>>>(sku_w, url_w, query_w, word_t, ws);
    alloc_k<<<256, 256, 0, stream>>>(event_type, out, ws);
    build_k<<<16384, 256, 0, stream>>>(ev_t, sku_t, cat_t, price_t, url_t,
                                       event_type, sku_id, url_id, cat_id, price_id,
                                       word_id, out, ws);
    dim3 gg(2048, 1, 3);
    gemm_all_k<<<gg, 256, 0, stream>>>(ws, sku_b, url_b, query_b, out);
}

// Round 11
// 86.143 us; speedup vs baseline: 1.0071x; 1.0016x over previous
//
#include <hip/hip_runtime.h>
#include <hip/hip_bf16.h>
#if !__has_builtin(__builtin_amdgcn_cvt_pk_fp8_f32) || !__has_builtin(__builtin_amdgcn_cvt_pk_f32_fp8)
#include <hip/hip_fp8.h>
#endif

// ---------------- workspace layout (bytes); ws_size ~1 GB ----------------
#define CUR_OFF   0          // int cur[3]
#define SLOT_OFF  1024       // int slot_of_pos[65536]
#define POS_OFF   263168     // int posm[3][65536]
#define WSKU_OFF  1049600    // fp8 [512][384] (x64)
#define WURL_OFF  1246208    // fp8 [512][192] (x64, cols 160..192 zero)
#define WQRY_OFF  1344512    // fp8 [512][192]
#define WF8_OFF   2097152    // fp8 word table [100000][128] (x64) = 12.8 MB
#define XS_OFF    16777216   // fp8 rows, stride 384 B, 65664 rows
#define XU_OFF    50331648   // fp8 rows, stride 192 B, 65664 rows
#define XQ_OFF    68157440   // fp8 rows, stride 192 B, 65664 rows

#define NPOS      65536
#define OUT_MASK  33554432   // 65536*512
#define F8_SCALE  64.0f
#define INV4096   (1.0f / 4096.0f)

typedef __attribute__((ext_vector_type(4))) float f32x4;
typedef __attribute__((ext_vector_type(2))) float f32x2;
typedef __attribute__((ext_vector_type(2))) unsigned int u32x2;

__device__ __forceinline__ float2 ld2(const float* p) {
    return *reinterpret_cast<const float2*>(p);
}

// fp8 e4m3 (OCP) pack/unpack
__device__ __forceinline__ unsigned int pk2_f8(float a, float b) {
#if __has_builtin(__builtin_amdgcn_cvt_pk_fp8_f32)
    return __builtin_amdgcn_cvt_pk_fp8_f32(a, b, 0u, false);
#else
    __hip_fp8_e4m3 fa(a), fb(b);
    return (unsigned int)fa.__x | ((unsigned int)fb.__x << 8);
#endif
}
__device__ __forceinline__ unsigned int pk4_f8(float a, float b, float c, float d) {
#if __has_builtin(__builtin_amdgcn_cvt_pk_fp8_f32)
    unsigned int v = 0;
    v = __builtin_amdgcn_cvt_pk_fp8_f32(a, b, v, false);
    v = __builtin_amdgcn_cvt_pk_fp8_f32(c, d, v, true);
    return v;
#else
    return pk2_f8(a, b) | (pk2_f8(c, d) << 16);
#endif
}
__device__ __forceinline__ float2 upk2_f8(unsigned int u) {
#if __has_builtin(__builtin_amdgcn_cvt_pk_f32_fp8)
    f32x2 r = __builtin_amdgcn_cvt_pk_f32_fp8(u, false);
    return make_float2(r.x, r.y);
#else
    __hip_fp8_e4m3 fa, fb;
    fa.__x = (unsigned char)(u & 0xff);
    fb.__x = (unsigned char)((u >> 8) & 0xff);
    return make_float2((float)fa, (float)fb);
#endif
}
__device__ __forceinline__ void st_f8x2(unsigned char* d, float a, float b) {
    *reinterpret_cast<unsigned short*>(d) = (unsigned short)(pk2_f8(a, b) & 0xffffu);
}

#define AS1(p) ((const __attribute__((address_space(1))) void*)(p))
#define AS3(p) ((__attribute__((address_space(3))) void*)(p))

// counted-wait pipeline primitives (T4; rule #18 fencing)
#define WAITV0() asm volatile("s_waitcnt vmcnt(0)" ::: "memory")
#define WAITV4() asm volatile("s_waitcnt vmcnt(4)" ::: "memory")
#define WAITV8() asm volatile("s_waitcnt vmcnt(8)" ::: "memory")
#define WAITL()  asm volatile("s_waitcnt lgkmcnt(0)" ::: "memory")
#define BARR()   __builtin_amdgcn_s_barrier()
#define FENCE()  __builtin_amdgcn_sched_barrier(0)

// ---- K1: word table f32->fp8(x64) + weights f32->fp8(x64) + cursor zero ----
__global__ __launch_bounds__(256) void prep_k(const float* __restrict__ sw,
                                              const float* __restrict__ uw,
                                              const float* __restrict__ qw,
                                              const float* __restrict__ word_t,
                                              char* ws) {
    const int b = blockIdx.x, t = threadIdx.x;
    if (b < 6250) {
        size_t i = ((size_t)b * 256 + t) * 8;
        f32x4 v0 = *reinterpret_cast<const f32x4*>(word_t + i);
        f32x4 v1 = *reinterpret_cast<const f32x4*>(word_t + i + 4);
        u32x2 pk;
        pk.x = pk4_f8(v0.x * F8_SCALE, v0.y * F8_SCALE, v0.z * F8_SCALE, v0.w * F8_SCALE);
        pk.y = pk4_f8(v1.x * F8_SCALE, v1.y * F8_SCALE, v1.z * F8_SCALE, v1.w * F8_SCALE);
        *reinterpret_cast<u32x2*>((unsigned char*)(ws + WF8_OFF) + i) = pk;
        return;
    }
    int tt = (b - 6250) * 256 + t;   // 393216 total
    if (tt < 3) ((int*)(ws + CUR_OFF))[tt] = 0;
    if (tt < 196608) {
        ((unsigned char*)(ws + WSKU_OFF))[tt] =
            (unsigned char)(pk2_f8(sw[tt] * F8_SCALE, 0.f) & 0xffu);
    } else if (tt < 294912) {
        int i = tt - 196608; int n = i / 192, k = i % 192;
        ((unsigned char*)(ws + WURL_OFF))[i] = (k < 160)
            ? (unsigned char)(pk2_f8(uw[n * 160 + k] * F8_SCALE, 0.f) & 0xffu) : 0;
    } else {
        int i = tt - 294912; int n = i / 192, k = i % 192;
        ((unsigned char*)(ws + WQRY_OFF))[i] = (k < 160)
            ? (unsigned char)(pk2_f8(qw[n * 160 + k] * F8_SCALE, 0.f) & 0xffu) : 0;
    }
}

// ---------------- K2: classify + slot allocation (block-aggregated) ----------
__global__ __launch_bounds__(256) void alloc_k(const int* __restrict__ et_a,
                                               float* __restrict__ out, char* ws) {
    __shared__ int s_wcnt[4][3];
    __shared__ int s_base[3];
    __shared__ int s_woff[4][3];
    const int t = threadIdx.x, lane = t & 63, wid = t >> 6;
    int p = blockIdx.x * 256 + t;
    int et = et_a[p];
    int br = (et >= 1 && et <= 3) ? 0 : (et == 4 ? 1 : (et == 5 ? 2 : -1));
    unsigned long long m0 = __ballot(br == 0);
    unsigned long long m1 = __ballot(br == 1);
    unsigned long long m2 = __ballot(br == 2);
    if (lane == 0) {
        s_wcnt[wid][0] = (int)__popcll(m0);
        s_wcnt[wid][1] = (int)__popcll(m1);
        s_wcnt[wid][2] = (int)__popcll(m2);
    }
    __syncthreads();
    if (t < 3) {
        int c0 = s_wcnt[0][t], c1 = s_wcnt[1][t], c2 = s_wcnt[2][t], c3 = s_wcnt[3][t];
        int tot = c0 + c1 + c2 + c3;
        s_base[t] = tot ? atomicAdd(&((int*)(ws + CUR_OFF))[t], tot) : 0;
        s_woff[0][t] = 0; s_woff[1][t] = c0; s_woff[2][t] = c0 + c1; s_woff[3][t] = c0 + c1 + c2;
    }
    __syncthreads();
    unsigned long long lt = (1ull << lane) - 1ull;
    int slot = -1;
    if (br == 0)      slot = s_base[0] + s_woff[wid][0] + (int)__popcll(m0 & lt);
    else if (br == 1) slot = s_base[1] + s_woff[wid][1] + (int)__popcll(m1 & lt);
    else if (br == 2) slot = s_base[2] + s_woff[wid][2] + (int)__popcll(m2 & lt);
    ((int*)(ws + SLOT_OFF))[p] = slot;
    if (slot >= 0) ((int*)(ws + POS_OFF))[br * NPOS + slot] = p;
    __builtin_nontemporal_store((et == 0) ? 1.0f : 0.0f, &out[OUT_MASK + p]);
}

// ---------------- K3: build fp8 input rows (x64 domain), 1 pos/wave ---------
__device__ __forceinline__ float2 wsum_f8(const unsigned char* __restrict__ wt8,
                                          const int* __restrict__ wids, int lane) {
    float sx = 0.f, sy = 0.f;
    #pragma unroll
    for (int k = 0; k < 12; ++k) {
        unsigned int u = *reinterpret_cast<const unsigned short*>(
            wt8 + (size_t)wids[k] * 128 + 2 * lane);
        float2 v = upk2_f8(u);
        sx += v.x; sy += v.y;
    }
    const float inv = 1.0f / 12.0f;      // stays in x64 domain
    return make_float2(sx * inv, sy * inv);
}

__global__ __launch_bounds__(256) void build_k(
    const float* __restrict__ ev_t,
    const float* __restrict__ sku_t,  const float* __restrict__ cat_t,
    const float* __restrict__ price_t,const float* __restrict__ url_t,
    const int* __restrict__ et_a,     const int* __restrict__ sku_id,
    const int* __restrict__ url_id,   const int* __restrict__ cat_id,
    const int* __restrict__ price_id, const int* __restrict__ word_id,
    float* __restrict__ out, char* ws)
{
    const int t = threadIdx.x, lane = t & 63, wid = t >> 6;
    const int p = blockIdx.x * 4 + wid;
    const int et = et_a[p];
    if (et == 0) {  // pad: zero output row
        f32x4 z = {0.f, 0.f, 0.f, 0.f};
        float* orow = out + (size_t)p * 512;
        __builtin_nontemporal_store(z, reinterpret_cast<f32x4*>(&orow[lane * 8]));
        __builtin_nontemporal_store(z, reinterpret_cast<f32x4*>(&orow[lane * 8 + 4]));
        return;
    }
    const int slot = ((const int*)(ws + SLOT_OFF))[p];
    const unsigned char* wf8 = (const unsigned char*)(ws + WF8_OFF);
    const float* evr = ev_t + et * 32;
    if (et <= 3) {  // sku row: [ev 0..32)[sku 32..160)[cat 160..224)[price 224..256)[word 256..384)
        unsigned char* X = (unsigned char*)(ws + XS_OFF) + (size_t)slot * 384;
        if (lane < 16) { float2 e = ld2(evr + 2 * lane);
                         st_f8x2(X + 2 * lane, e.x * F8_SCALE, e.y * F8_SCALE); }
        const float* sr = sku_t + (size_t)sku_id[p] * 128;
        { float2 s = ld2(sr + 2 * lane);
          st_f8x2(X + 32 + 2 * lane, s.x * F8_SCALE, s.y * F8_SCALE); }
        if (lane < 32) { const float* cr = cat_t + (size_t)cat_id[p] * 64;
                         float2 c = ld2(cr + 2 * lane);
                         st_f8x2(X + 160 + 2 * lane, c.x * F8_SCALE, c.y * F8_SCALE); }
        if (lane < 16) { const float* pr = price_t + (size_t)price_id[p] * 32;
                         float2 v = ld2(pr + 2 * lane);
                         st_f8x2(X + 224 + 2 * lane, v.x * F8_SCALE, v.y * F8_SCALE); }
        float2 w = wsum_f8(wf8, word_id + (size_t)p * 12, lane);
        st_f8x2(X + 256 + 2 * lane, w.x, w.y);
    } else if (et == 4) {  // url row: [url 0..128)[ev 128..160)[zero 160..192)
        unsigned char* X = (unsigned char*)(ws + XU_OFF) + (size_t)slot * 192;
        const float* ur = url_t + (size_t)url_id[p] * 128;
        { float2 u = ld2(ur + 2 * lane);
          st_f8x2(X + 2 * lane, u.x * F8_SCALE, u.y * F8_SCALE); }
        if (lane < 16) { float2 e = ld2(evr + 2 * lane);
                         st_f8x2(X + 128 + 2 * lane, e.x * F8_SCALE, e.y * F8_SCALE); }
        if (lane >= 48) *reinterpret_cast<unsigned short*>(X + 160 + 2 * (lane - 48)) = 0;
    } else {               // query row: [ev 0..32)[word 32..160)[zero 160..192)
        unsigned char* X = (unsigned char*)(ws + XQ_OFF) + (size_t)slot * 192;
        if (lane < 16) { float2 e = ld2(evr + 2 * lane);
                         st_f8x2(X + 2 * lane, e.x * F8_SCALE, e.y * F8_SCALE); }
        float2 w = wsum_f8(wf8, word_id + (size_t)p * 12, lane);
        st_f8x2(X + 32 + 2 * lane, w.x, w.y);
        if (lane >= 48) *reinterpret_cast<unsigned short*>(X + 160 + 2 * (lane - 48)) = 0;
    }
}

// ---------------- K4: merged fp8 branch GEMMs  out[pos]=relu(X*W^T/4096+b) --
// 128x128 tile, 4 waves (2x2) x 64x64, mfma_f32_16x16x32_fp8_fp8.
// T4 counted-vmcnt pipeline: all stages issued early; per K-step
//   s_waitcnt vmcnt(N_outstanding_next) + raw s_barrier (loads stay in flight);
//   buffer-reuse protected by lgkmcnt(0)+barrier (no vmcnt drain).
__global__ __launch_bounds__(256, 2) void gemm_all_k(
    const char* __restrict__ ws_c, const float* __restrict__ sku_b,
    const float* __restrict__ url_b, const float* __restrict__ qry_b,
    float* __restrict__ out)
{
    const int z = blockIdx.z;
    const int count = ((const int*)(ws_c + CUR_OFF))[z];
    const int nmt = (count + 127) >> 7;
    const int nwg = nmt * 4;
    const int orig = blockIdx.x;
    if (orig >= nwg) return;
    const int q8 = nwg >> 3, r8 = nwg & 7;
    const int xcd = orig & 7, idx = orig >> 3;
    const int wg = (xcd < r8 ? xcd * (q8 + 1) : r8 * (q8 + 1) + (xcd - r8) * q8) + idx;
    const int mt = wg >> 2;
    const int row0 = mt * 128;
    const int nc0  = (wg & 3) * 128;

    const char* arena; const char* Wb; const float* bias; const int* posm;
    int astride;
    if (z == 0) { arena = ws_c + XS_OFF; Wb = ws_c + WSKU_OFF; bias = sku_b;
                  posm = (const int*)(ws_c + POS_OFF);          astride = 384; }
    else if (z == 1) { arena = ws_c + XU_OFF; Wb = ws_c + WURL_OFF; bias = url_b;
                  posm = (const int*)(ws_c + POS_OFF) + NPOS;   astride = 192; }
    else       { arena = ws_c + XQ_OFF; Wb = ws_c + WQRY_OFF; bias = qry_b;
                  posm = (const int*)(ws_c + POS_OFF) + 2*NPOS; astride = 192; }

    __shared__ char lds[2][2][16384];   // [buf][A/B][<=128 rows x 128 B]

    const int t = threadIdx.x;
    const int lane = t & 63;
    const int wid  = t >> 6;
    const int wr = wid >> 1, wc = wid & 1;
    const int r = lane & 15, q = lane >> 4;

    // 8 gload_lds per thread
    auto stage_full = [&](int buf, int koff) {
        #pragma unroll
        for (int i = 0; i < 4; ++i) {
            int row = i * 32 + (t >> 3);
            int sb  = (t & 7) ^ (row & 7);
            const char* ga = arena + (size_t)(row0 + row) * astride + koff + sb * 16;
            __builtin_amdgcn_global_load_lds(AS1(ga), AS3(&lds[buf][0][i * 4096 + t * 16]), 16, 0, 0);
            const char* gb = Wb + (size_t)(nc0 + row) * astride + koff + sb * 16;
            __builtin_amdgcn_global_load_lds(AS1(gb), AS3(&lds[buf][1][i * 4096 + t * 16]), 16, 0, 0);
        }
    };
    // 4 gload_lds per thread (64-B-wide tile)
    auto stage_half = [&](int buf, int koff) {
        #pragma unroll
        for (int i = 0; i < 2; ++i) {
            int row = i * 64 + (t >> 2);
            int sb  = (t & 3) ^ (row & 3);
            const char* ga = arena + (size_t)(row0 + row) * astride + koff + sb * 16;
            __builtin_amdgcn_global_load_lds(AS1(ga), AS3(&lds[buf][0][i * 4096 + t * 16]), 16, 0, 0);
            const char* gb = Wb + (size_t)(nc0 + row) * astride + koff + sb * 16;
            __builtin_amdgcn_global_load_lds(AS1(gb), AS3(&lds[buf][1][i * 4096 + t * 16]), 16, 0, 0);
        }
    };

    f32x4 acc[4][4];
    #pragma unroll
    for (int m = 0; m < 4; ++m)
        #pragma unroll
        for (int n = 0; n < 4; ++n)
            acc[m][n] = (f32x4){0.f, 0.f, 0.f, 0.f};

    auto comp_full = [&](int buf) {
        #pragma unroll
        for (int kk = 0; kk < 4; ++kk) {
            const int u  = kk * 2 + (q >> 1);
            const int wo = (q & 1) * 8;
            long af[4], bfr[4];
            #pragma unroll
            for (int m = 0; m < 4; ++m) {
                int arow = wr * 64 + m * 16 + r;
                af[m] = *reinterpret_cast<const long*>(
                    &lds[buf][0][arow * 128 + ((u ^ (arow & 7)) << 4) + wo]);
            }
            #pragma unroll
            for (int n = 0; n < 4; ++n) {
                int brow = wc * 64 + n * 16 + r;
                bfr[n] = *reinterpret_cast<const long*>(
                    &lds[buf][1][brow * 128 + ((u ^ (brow & 7)) << 4) + wo]);
            }
            #pragma unroll
            for (int m = 0; m < 4; ++m)
                #pragma unroll
                for (int n = 0; n < 4; ++n)
                    acc[m][n] = __builtin_amdgcn_mfma_f32_16x16x32_fp8_fp8(af[m], bfr[n], acc[m][n], 0, 0, 0);
        }
    };
    auto comp_half = [&](int buf) {
        #pragma unroll
        for (int kk = 0; kk < 2; ++kk) {
            const int u  = kk * 2 + (q >> 1);
            const int wo = (q & 1) * 8;
            long af[4], bfr[4];
            #pragma unroll
            for (int m = 0; m < 4; ++m) {
                int arow = wr * 64 + m * 16 + r;
                af[m] = *reinterpret_cast<const long*>(
                    &lds[buf][0][arow * 64 + ((u ^ (arow & 3)) << 4) + wo]);
            }
            #pragma unroll
            for (int n = 0; n < 4; ++n) {
                int brow = wc * 64 + n * 16 + r;
                bfr[n] = *reinterpret_cast<const long*>(
                    &lds[buf][1][brow * 64 + ((u ^ (brow & 3)) << 4) + wo]);
            }
            #pragma unroll
            for (int m = 0; m < 4; ++m)
                #pragma unroll
                for (int n = 0; n < 4; ++n)
                    acc[m][n] = __builtin_amdgcn_mfma_f32_16x16x32_fp8_fp8(af[m], bfr[n], acc[m][n], 0, 0, 0);
        }
    };

    if (z == 0) {                       // K=384: three full tiles
        stage_full(0, 0);
        stage_full(1, 128);             // 16 loads in flight
        WAITV8(); BARR(); FENCE();      // tile0 landed; tile1 stays in flight
        comp_full(0);
        WAITL(); BARR(); FENCE();       // all waves done reading buf0
        stage_full(0, 256);             // overwrite buf0 with tile2
        WAITV8(); BARR(); FENCE();      // tile1 landed; tile2 in flight
        comp_full(1);
        WAITV0(); BARR(); FENCE();      // tile2 landed
        comp_full(0);
    } else {                            // K=192: full + half tile
        stage_full(0, 0);
        stage_half(1, 128);             // 12 loads in flight
        WAITV4(); BARR(); FENCE();      // tile0 landed; half-tile in flight
        comp_full(0);
        WAITV0(); BARR(); FENCE();      // half-tile landed
        comp_half(1);
    }

    float bv[4];
    #pragma unroll
    for (int n = 0; n < 4; ++n) bv[n] = bias[nc0 + wc * 64 + n * 16 + r];
    #pragma unroll
    for (int m = 0; m < 4; ++m) {
        #pragma unroll
        for (int j = 0; j < 4; ++j) {
            int rl = wr * 64 + m * 16 + q * 4 + j;
            int gr = row0 + rl;
            if (gr < count) {
                int pos = posm[gr];
                float* orow = out + (size_t)pos * 512 + nc0 + wc * 64;
                #pragma unroll
                for (int n = 0; n < 4; ++n)
                    __builtin_nontemporal_store(
                        fmaxf(acc[m][n][j] * INV4096 + bv[n], 0.f), &orow[n * 16 + r]);
            }
        }
    }
}

// ---------------- host ----------------
extern "C" void kernel_launch(void* const* d_in, const int* in_sizes, int n_in,
                              void* d_out, int out_size, void* d_ws, size_t ws_size,
                              hipStream_t stream) {
    const float* ev_t    = (const float*)d_in[0];
    const float* word_t  = (const float*)d_in[1];
    const float* sku_t   = (const float*)d_in[2];
    const float* cat_t   = (const float*)d_in[3];
    const float* price_t = (const float*)d_in[4];
    const float* url_t   = (const float*)d_in[5];
    const float* sku_w   = (const float*)d_in[6];
    const float* sku_b   = (const float*)d_in[7];
    const float* url_w   = (const float*)d_in[8];
    const float* url_b   = (const float*)d_in[9];
    const float* query_w = (const float*)d_in[10];
    const float* query_b = (const float*)d_in[11];
    const int* event_type = (const int*)d_in[12];
    const int* sku_id     = (const int*)d_in[13];
    const int* url_id     = (const int*)d_in[14];
    const int* cat_id     = (const int*)d_in[15];
    const int* price_id   = (const int*)d_in[16];
    const int* word_id    = (const int*)d_in[17];

    char*  ws  = (char*)d_ws;
    float* out = (float*)d_out;

    prep_k<<<7786, 256, 0, stream>>>(sku_w, url_w, query_w, word_t, ws);
    alloc_k<<<256, 256, 0, stream>>>(event_type, out, ws);
    build_k<<<16384, 256, 0, stream>>>(ev_t, sku_t, cat_t, price_t, url_t,
                                       event_type, sku_id, url_id, cat_id, price_id,
                                       word_id, out, ws);
    dim3 gg(2048, 1, 3);
    gemm_all_k<<<gg, 256, 0, stream>>>(ws, sku_b, url_b, query_b, out);
}